// Round 2
// baseline (247.108 us; speedup 1.0000x reference)
//
#include <hip/hip_runtime.h>
#include <hip/hip_bf16.h>

// Problem constants
constexpr int R  = 59;
constexpr int D  = 128;
constexpr int NK = 16;      // neighbors per (r,n)
constexpr int N  = 1024;
constexpr int T  = 32;
constexpr int F  = 10;
constexpr int H4 = 512;     // 4*D
constexpr int WSTRIDE = 2*D + R; // 315

__device__ __forceinline__ float sigm(float x)  { return 1.0f/(1.0f+__expf(-x)); }
__device__ __forceinline__ float tanh_(float x) { return 2.0f/(1.0f+__expf(-2.0f*x)) - 1.0f; }

// ---------------------------------------------------------------------------
// Runtime dtype detection: interpret first 128 elems of `windows` as bf16.
// True bf16 N(0,1) data -> ~0 "weird" values. fp32 data misread as bf16 ->
// even elems are raw mantissa bits (uniform exponent) -> ~55/128 weird.
// Returns 1 if the buffers are fp32, 0 if bf16. Deterministic.
// ---------------------------------------------------------------------------
__device__ int g_detect_f32(const void* windows) {
  const __hip_bfloat16* p = (const __hip_bfloat16*)windows;
  int weird = 0;
  for (int i = 0; i < 128; ++i) {
    float v = __bfloat162float(p[i]);
    float a = fabsf(v);
    if (!(a <= 100.0f) || (v != 0.0f && a < 1e-8f)) ++weird;  // catches NaN/Inf too
  }
  return weird > 8;
}

struct CvtArgs {
  const void* src[10];
  int off[11];   // exclusive prefix sums; off[10] = total
};

// One kernel converts all 10 float tensors into a contiguous fp32 ws area.
__global__ __launch_bounds__(256) void convert_kernel(CvtArgs a, float* __restrict__ dst) {
  __shared__ int sflag;
  if (threadIdx.x == 0) sflag = g_detect_f32(a.src[0]);
  __syncthreads();
  const int isf32 = sflag;
  const int total = a.off[10];
  for (int i = blockIdx.x * 256 + threadIdx.x; i < total; i += gridDim.x * 256) {
    int t = 0;
    while (t < 9 && i >= a.off[t + 1]) ++t;
    const int j = i - a.off[t];
    dst[i] = isf32 ? ((const float*)a.src[t])[j]
                   : __bfloat162float(((const __hip_bfloat16*)a.src[t])[j]);
  }
}

// ---------------------------------------------------------------------------
// Kernel 1: fused input-projection + LSTM scan. 4 samples per block.
// threads: 512 = 128 d-values * 4 k-groups. Thread (d,kg) owns
// Wr[kg*32..+32][{d,128+d,256+d,384+d}] in registers.
// ---------------------------------------------------------------------------
__global__ __launch_bounds__(512) void lstm_kernel(
    const float* __restrict__ windows, const float* __restrict__ Wk,
    const float* __restrict__ Wr, const float* __restrict__ bias,
    float* __restrict__ feats)
{
  const int tid = threadIdx.x;
  const int d   = tid >> 2;
  const int kg  = tid & 3;
  const int n0  = blockIdx.x * 4;

  __shared__ float h_lds[4 * 136];     // [n][k + k/32], padded
  __shared__ float wk_lds[F * H4];     // 20 KB
  __shared__ float b_lds[H4];
  __shared__ float win_lds[4 * T * F]; // 1280 floats

  // zero feats row 0 (the "padding" feature row)
  if (blockIdx.x == 0 && tid < D) feats[tid] = 0.0f;

  // persistent Wr slice in registers: [gate][kk]
  float wr_reg[4][32];
  {
    const int kbase = kg * 32;
#pragma unroll
    for (int g = 0; g < 4; ++g) {
      const int col = g * D + d;
#pragma unroll
      for (int kk = 0; kk < 32; ++kk)
        wr_reg[g][kk] = Wr[(kbase + kk) * H4 + col];
    }
  }
  for (int i = tid; i < F * H4;    i += 512) wk_lds[i]  = Wk[i];
  for (int i = tid; i < H4;        i += 512) b_lds[i]   = bias[i];
  for (int i = tid; i < 4 * T * F; i += 512) win_lds[i] = windows[n0 * T * F + i];
  for (int i = tid; i < 4 * 136;   i += 512) h_lds[i] = 0.0f;
  __syncthreads();

  float c[4]    = {0.f, 0.f, 0.f, 0.f};
  float hnew[4] = {0.f, 0.f, 0.f, 0.f};
  const int hbase = kg * 33;   // kg*32 (k offset) + kg (swizzle pad)

  for (int t = 0; t < T; ++t) {
    float acc[4][4];   // [n][gate]
#pragma unroll
    for (int n = 0; n < 4; ++n)
#pragma unroll
      for (int g = 0; g < 4; ++g) acc[n][g] = 0.0f;

    // recurrent partial sums over this thread's 32-wide k slice
#pragma unroll
    for (int kk = 0; kk < 32; ++kk) {
      float hv[4];
#pragma unroll
      for (int n = 0; n < 4; ++n) hv[n] = h_lds[n * 136 + hbase + kk];
#pragma unroll
      for (int n = 0; n < 4; ++n)
#pragma unroll
        for (int g = 0; g < 4; ++g)
          acc[n][g] = fmaf(hv[n], wr_reg[g][kk], acc[n][g]);
    }
    // reduce the 4 k-groups (adjacent lanes)
#pragma unroll
    for (int n = 0; n < 4; ++n)
#pragma unroll
      for (int g = 0; g < 4; ++g) {
        float v = acc[n][g];
        v += __shfl_xor(v, 1);
        v += __shfl_xor(v, 2);
        acc[n][g] = v;
      }
    // add input projection + bias (identical on all 4 kg lanes)
#pragma unroll
    for (int n = 0; n < 4; ++n) {
      const float* w = &win_lds[n * T * F + t * F];
#pragma unroll
      for (int g = 0; g < 4; ++g) {
        const int col = g * D + d;
        float z = acc[n][g] + b_lds[col];
#pragma unroll
        for (int f = 0; f < F; ++f) z = fmaf(w[f], wk_lds[f * H4 + col], z);
        acc[n][g] = z;
      }
    }
    __syncthreads();   // all h reads done before overwrite
#pragma unroll
    for (int n = 0; n < 4; ++n) {
      float i_ = sigm(acc[n][0]);
      float f_ = sigm(acc[n][1]);
      float g_ = tanh_(acc[n][2]);
      float o_ = sigm(acc[n][3]);
      c[n]    = f_ * c[n] + i_ * g_;
      hnew[n] = o_ * tanh_(c[n]);
    }
    if (kg == 0) {
#pragma unroll
      for (int n = 0; n < 4; ++n) h_lds[n * 136 + d + (d >> 5)] = hnew[n];
    }
    __syncthreads();
  }

  // cur -> feats rows 1..N
  if (kg == 0) {
#pragma unroll
    for (int n = 0; n < 4; ++n) feats[(n0 + n + 1) * D + d] = hnew[n];
  }
}

// ---------------------------------------------------------------------------
// Kernel 2: cur_term[n][r] = cur.Wc[r], nbr_proj[m][r] = feats[m].Wn[r],
//           curwc[n] = cur . wc.   One wave per feats row m.
// ---------------------------------------------------------------------------
__global__ __launch_bounds__(64) void proj_kernel(
    const float* __restrict__ feats, const float* __restrict__ W_state,
    const float* __restrict__ W_relattn,
    float* __restrict__ cur_term, float* __restrict__ nbr_proj,
    float* __restrict__ curwc)
{
  const int m    = blockIdx.x;   // 0..1024
  const int lane = threadIdx.x;  // 0..63
  const float f0 = feats[m * D + lane];
  const float f1 = feats[m * D + 64 + lane];

  for (int r = 0; r < R; ++r) {
    const float* wsrow = W_state + r * WSTRIDE;
    float a = f0 * wsrow[D + lane] + f1 * wsrow[D + 64 + lane];   // Wn
    for (int off = 32; off; off >>= 1) a += __shfl_xor(a, off);
    if (lane == 0) nbr_proj[m * R + r] = a;
    if (m >= 1) {
      float b = f0 * wsrow[lane] + f1 * wsrow[64 + lane];         // Wc
      for (int off = 32; off; off >>= 1) b += __shfl_xor(b, off);
      if (lane == 0) cur_term[(m - 1) * R + r] = b;
    }
  }
  if (m >= 1) {
    float v = f0 * W_relattn[lane] + f1 * W_relattn[64 + lane];
    for (int off = 32; off; off >>= 1) v += __shfl_xor(v, off);
    if (lane == 0) curwc[m - 1] = v;
  }
}

// ---------------------------------------------------------------------------
// Kernel 3: fused scores -> softmax(K) -> rel_reps (LDS) -> s2 -> softmax(R)
//           -> rel_agg -> updated -> logits -> predictions.  One block per n.
// Output dtype decided per-block from the raw windows buffer.
// ---------------------------------------------------------------------------
__device__ __forceinline__ void store_out(void* out, int i, float v, int outf32) {
  if (outf32) ((float*)out)[i] = v;
  else        ((__hip_bfloat16*)out)[i] = __float2bfloat16(v);
}

__global__ __launch_bounds__(256) void attn_kernel(
    const float* __restrict__ feats, const int* __restrict__ neighbors,
    const float* __restrict__ W_state, const float* __restrict__ b_state,
    const float* __restrict__ W_relattn, const float* __restrict__ b_relattn,
    const float* __restrict__ W_pred, const float* __restrict__ b_pred,
    const float* __restrict__ cur_term, const float* __restrict__ nbr_proj,
    const float* __restrict__ curwc, const void* __restrict__ win_raw,
    void* __restrict__ out)
{
  const int n   = blockIdx.x;
  const int tid = threadIdx.x;

  __shared__ float rr[R * 129];     // rel_reps, stride 129 vs bank conflicts
  __shared__ int   idx_lds[R * NK];
  __shared__ float sc_lds[R * NK];
  __shared__ float w_lds[R * NK];
  __shared__ float ct_lds[R];
  __shared__ float rt_lds[R];
  __shared__ float s2_lds[R];
  __shared__ float aw_lds[R];
  __shared__ float upd_lds[D];
  __shared__ int   sflag;

  // A: per-r constants + neighbor indices + out-dtype flag
  if (tid == 0) sflag = g_detect_f32(win_raw);
  if (tid < R) {
    ct_lds[tid] = cur_term[n * R + tid];
    rt_lds[tid] = W_state[tid * WSTRIDE + 2 * D + tid] + b_state[tid];
  }
  for (int i = tid; i < R * NK; i += 256) {
    const int r = i >> 4, k = i & 15;
    idx_lds[i] = neighbors[(r * N + n) * NK + k];
  }
  __syncthreads();
  const int outf32 = sflag;

  // B1: scores (parallel gathers)
  for (int i = tid; i < R * NK; i += 256) {
    const int r = i >> 4;
    float s = ct_lds[r] + nbr_proj[idx_lds[i] * R + r] + rt_lds[r];
    sc_lds[i] = fmaxf(s, 0.0f);
  }
  __syncthreads();

  // B2: softmax over K per r
  if (tid < R) {
    float mx = -1e30f;
#pragma unroll
    for (int k = 0; k < NK; ++k) mx = fmaxf(mx, sc_lds[tid * NK + k]);
    float sum = 0.0f;
#pragma unroll
    for (int k = 0; k < NK; ++k) {
      float e = __expf(sc_lds[tid * NK + k] - mx);
      w_lds[tid * NK + k] = e;
      sum += e;
    }
    const float inv = 1.0f / sum;
#pragma unroll
    for (int k = 0; k < NK; ++k) w_lds[tid * NK + k] *= inv;
  }
  __syncthreads();

  // C: rel_reps[r][d] = sum_k w * feats[idx][d]   (2 r's at a time)
  {
    const int dd   = tid & 127;
    const int half = tid >> 7;
    for (int rp = 0; rp < 30; ++rp) {
      const int r = rp * 2 + half;
      if (r < R) {
        float acc = 0.0f;
#pragma unroll
        for (int k = 0; k < NK; ++k) {
          const int m = idx_lds[r * NK + k];
          acc = fmaf(w_lds[r * NK + k], feats[m * D + dd], acc);
        }
        rr[r * 129 + dd] = acc;
      }
    }
  }
  __syncthreads();

  // D1: s2[r] = relu(curwc + rel_reps[r].wn + wr[r] + b)
  if (tid < R) {
    float dot = 0.0f;
    for (int dd = 0; dd < D; ++dd)
      dot = fmaf(rr[tid * 129 + dd], W_relattn[D + dd], dot);
    float v = curwc[n] + dot + W_relattn[2 * D + tid] + b_relattn[0];
    s2_lds[tid] = fmaxf(v, 0.0f);
  }
  __syncthreads();

  // D2: softmax over r (wave 0)
  if (tid < 64) {
    float v = (tid < R) ? s2_lds[tid] : -1e30f;
    float mx = v;
    for (int off = 32; off; off >>= 1) mx = fmaxf(mx, __shfl_xor(mx, off));
    float e = (tid < R) ? __expf(v - mx) : 0.0f;
    float sum = e;
    for (int off = 32; off; off >>= 1) sum += __shfl_xor(sum, off);
    if (tid < R) aw_lds[tid] = e / sum;
  }
  __syncthreads();

  // E: rel_agg + updated
  if (tid < D) {
    float agg = 0.0f;
    for (int r = 0; r < R; ++r) agg = fmaf(aw_lds[r], rr[r * 129 + tid], agg);
    const float upd = feats[(n + 1) * D + tid] + agg;
    store_out(out, 2 * 3 * N + n * D + tid, upd, outf32);
    upd_lds[tid] = upd;
  }
  __syncthreads();

  // F: logits + prediction softmax (wave 0)
  if (tid < 64) {
    float p[3];
#pragma unroll
    for (int j = 0; j < 3; ++j) {
      float v = upd_lds[tid] * W_pred[tid * 3 + j] +
                upd_lds[tid + 64] * W_pred[(tid + 64) * 3 + j];
      for (int off = 32; off; off >>= 1) v += __shfl_xor(v, off);
      p[j] = v + b_pred[j];
    }
    if (tid == 0) {
      const float mx = fmaxf(p[0], fmaxf(p[1], p[2]));
      const float e0 = __expf(p[0] - mx), e1 = __expf(p[1] - mx), e2 = __expf(p[2] - mx);
      const float s = e0 + e1 + e2;
      store_out(out, n * 3 + 0, p[0], outf32);
      store_out(out, n * 3 + 1, p[1], outf32);
      store_out(out, n * 3 + 2, p[2], outf32);
      store_out(out, 3 * N + n * 3 + 0, e0 / s, outf32);
      store_out(out, 3 * N + n * 3 + 1, e1 / s, outf32);
      store_out(out, 3 * N + n * 3 + 2, e2 / s, outf32);
    }
  }
}

// ---------------------------------------------------------------------------
extern "C" void kernel_launch(void* const* d_in, const int* in_sizes, int n_in,
                              void* d_out, int out_size, void* d_ws, size_t ws_size,
                              hipStream_t stream)
{
  const int* neighbors = (const int*)d_in[1];
  float* ws = (float*)d_ws;

  // fp32-converted inputs (concatenated, in input order, skipping neighbors)
  constexpr int SZ[10] = {327680, 5120, 65536, 512, 18585, 59, 315, 1, 384, 3};
  CvtArgs ca;
  {
    int off = 0;
    int k = 0;
    for (int i = 0; i < 11; ++i) {
      if (i == 1) continue;               // neighbors (int32) not converted
      ca.src[k] = d_in[i];
      ca.off[k] = off;
      off += SZ[k];
      ++k;
    }
    ca.off[10] = off;                     // 418195
  }
  float* cvt      = ws;                   // 418195 floats
  float* feats    = cvt + 418208;         // (N+1)*D = 131200
  float* cur_term = feats + 131200;       // N*R     = 60416
  float* nbr_proj = cur_term + 60416;     // (N+1)*R = 60475
  float* curwc    = nbr_proj + 60480;     // N       = 1024

  const float* c_windows = cvt;
  const float* c_Wk      = cvt + 327680;
  const float* c_Wr      = cvt + 332800;
  const float* c_bias    = cvt + 398336;
  const float* c_Wstate  = cvt + 398848;
  const float* c_bstate  = cvt + 417433;
  const float* c_Wrel    = cvt + 417492;
  const float* c_brel    = cvt + 417807;
  const float* c_Wpred   = cvt + 417808;
  const float* c_bpred   = cvt + 418192;

  convert_kernel<<<1024, 256, 0, stream>>>(ca, cvt);
  lstm_kernel<<<N / 4, 512, 0, stream>>>(c_windows, c_Wk, c_Wr, c_bias, feats);
  proj_kernel<<<N + 1, 64, 0, stream>>>(feats, c_Wstate, c_Wrel, cur_term, nbr_proj, curwc);
  attn_kernel<<<N, 256, 0, stream>>>(feats, neighbors, c_Wstate, c_bstate, c_Wrel,
                                     c_brel, c_Wpred, c_bpred,
                                     cur_term, nbr_proj, curwc, d_in[0], d_out);
}

// Round 3
// 172.582 us; speedup vs baseline: 1.4318x; 1.4318x over previous
//
#include <hip/hip_runtime.h>
#include <hip/hip_bf16.h>

// Problem constants
constexpr int R  = 59;
constexpr int D  = 128;
constexpr int NK = 16;      // neighbors per (r,n)
constexpr int N  = 1024;
constexpr int T  = 32;
constexpr int F  = 10;
constexpr int H4 = 512;     // 4*D
constexpr int WSTRIDE = 2*D + R; // 315

typedef __attribute__((ext_vector_type(8))) short short8;   // 8 bf16 (4 VGPR)
typedef __attribute__((ext_vector_type(4))) float f32x4;    // MFMA C/D

__device__ __forceinline__ float sigm(float x)  { return 1.0f/(1.0f+__expf(-x)); }
__device__ __forceinline__ float tanh_(float x) { return 2.0f/(1.0f+__expf(-2.0f*x)) - 1.0f; }
__device__ __forceinline__ ushort f2bf(float f) {          // RNE fp32->bf16
  unsigned u = __float_as_uint(f);
  u += 0x7FFF + ((u >> 16) & 1);
  return (ushort)(u >> 16);
}

// ---------------------------------------------------------------------------
// Runtime dtype detection (unchanged from round 2 — proven).
// ---------------------------------------------------------------------------
__device__ int g_detect_f32(const void* windows) {
  const __hip_bfloat16* p = (const __hip_bfloat16*)windows;
  int weird = 0;
  for (int i = 0; i < 128; ++i) {
    float v = __bfloat162float(p[i]);
    float a = fabsf(v);
    if (!(a <= 100.0f) || (v != 0.0f && a < 1e-8f)) ++weird;
  }
  return weird > 8;
}

struct CvtArgs {
  const void* src[10];
  int off[11];
};

__global__ __launch_bounds__(256) void convert_kernel(CvtArgs a, float* __restrict__ dst) {
  __shared__ int sflag;
  if (threadIdx.x == 0) sflag = g_detect_f32(a.src[0]);
  __syncthreads();
  const int isf32 = sflag;
  const int total = a.off[10];
  for (int i = blockIdx.x * 256 + threadIdx.x; i < total; i += gridDim.x * 256) {
    int t = 0;
    while (t < 9 && i >= a.off[t + 1]) ++t;
    const int j = i - a.off[t];
    dst[i] = isf32 ? ((const float*)a.src[t])[j]
                   : __bfloat162float(((const __hip_bfloat16*)a.src[t])[j]);
  }
}

// ---------------------------------------------------------------------------
// Kernel 1: MFMA LSTM. 128 blocks x 8 samples, 512 threads = 8 waves.
// Z[8,512] = [h|x] @ [Wr;Wk] per step via mfma_f32_16x16x32_bf16.
// Wave w owns cols [16w,16w+16) of EACH gate (N-tiles w, w+8, w+16, w+24),
// so the gate pointwise is lane-local in C-layout. One barrier per step.
// ---------------------------------------------------------------------------
__global__ __launch_bounds__(512, 2) void lstm_kernel(
    const float* __restrict__ cvt, float* __restrict__ feats)
{
  const float* Wwin = cvt;                 // [1024][32][10]
  const float* Wk   = cvt + 327680;        // [10][512]
  const float* Wr   = cvt + 332800;        // [128][512]
  const float* bias = cvt + 398336;        // [512]

  const int tid = threadIdx.x;
  const int w   = tid >> 6;    // wave 0..7
  const int l   = tid & 63;    // lane
  const int n0  = blockIdx.x * 8;

  __shared__ ushort hbuf[2][16 * 136];     // bf16 h, double-buffered, padded
  __shared__ ushort xfrag[T * 64 * 8];     // prebuilt A-frags for x (32 KB)

  if (blockIdx.x == 0 && tid < D) feats[tid] = 0.0f;   // feats row 0 = 0

  // Prebuild per-t x A-fragments: lane ll -> row=ll&15, k-chunk=ll>>4.
  for (int p = tid; p < T * 64; p += 512) {
    const int t = p >> 6, ll = p & 63, row = ll & 15, kg = ll >> 4;
#pragma unroll
    for (int j = 0; j < 8; ++j) {
      const int f = kg * 8 + j;
      float x = (row < 8 && f < F) ? Wwin[(n0 + row) * (T * F) + t * F + f] : 0.0f;
      xfrag[p * 8 + j] = f2bf(x);
    }
  }
  for (int i = tid; i < 2 * 16 * 136; i += 512) hbuf[0][i] = 0;  // both buffers

  // Persistent B fragments: [gate][kfrag]; kfrag 0..3 = Wr rows, 4 = Wk (pad 0).
  const int dcol  = w * 16 + (l & 15);     // this lane's d within [0,128)
  const int krow0 = (l >> 4) * 8;
  short8 B[4][5];
#pragma unroll
  for (int g = 0; g < 4; ++g) {
    const int col = g * D + dcol;
#pragma unroll
    for (int kf = 0; kf < 5; ++kf) {
      short8 bb;
#pragma unroll
      for (int j = 0; j < 8; ++j) {
        float v;
        if (kf < 4) v = Wr[(kf * 32 + krow0 + j) * H4 + col];
        else {
          const int f = krow0 + j;
          v = (f < F) ? Wk[f * H4 + col] : 0.0f;
        }
        bb[j] = (short)f2bf(v);
      }
      B[g][kf] = bb;
    }
  }
  float bi[4];
#pragma unroll
  for (int g = 0; g < 4; ++g) bi[g] = bias[g * D + dcol];

  f32x4 c4 = {0.f, 0.f, 0.f, 0.f};
  float hreg[4] = {0.f, 0.f, 0.f, 0.f};
  const int rb = (l >> 4) * 4;             // C-layout row base for this lane

  __syncthreads();

  for (int t = 0; t < T; ++t) {
    const ushort* hb = hbuf[t & 1];
    short8 A[5];
#pragma unroll
    for (int kf = 0; kf < 4; ++kf)
      A[kf] = *(const short8*)(hb + (l & 15) * 136 + kf * 32 + krow0);
    A[4] = *(const short8*)(xfrag + (t * 64 + l) * 8);

    f32x4 acc[4];
#pragma unroll
    for (int g = 0; g < 4; ++g) {
      acc[g] = (f32x4){0.f, 0.f, 0.f, 0.f};
#pragma unroll
      for (int kf = 0; kf < 5; ++kf)
        acc[g] = __builtin_amdgcn_mfma_f32_16x16x32_bf16(A[kf], B[g][kf], acc[g], 0, 0, 0);
    }

    ushort* hw = hbuf[(t + 1) & 1];
#pragma unroll
    for (int r = 0; r < 4; ++r) {
      const float i_ = sigm(acc[0][r] + bi[0]);
      const float f_ = sigm(acc[1][r] + bi[1]);
      const float g_ = tanh_(acc[2][r] + bi[2]);
      const float o_ = sigm(acc[3][r] + bi[3]);
      c4[r]   = f_ * c4[r] + i_ * g_;
      hreg[r] = o_ * tanh_(c4[r]);
      if (rb + r < 8) hw[(rb + r) * 136 + dcol] = f2bf(hreg[r]);
    }
    __syncthreads();
  }

#pragma unroll
  for (int r = 0; r < 4; ++r)
    if (rb + r < 8) feats[(n0 + rb + r + 1) * D + dcol] = hreg[r];
}

// ---------------------------------------------------------------------------
// Kernel 2: projections (unchanged).
// ---------------------------------------------------------------------------
__global__ __launch_bounds__(64) void proj_kernel(
    const float* __restrict__ feats, const float* __restrict__ W_state,
    const float* __restrict__ W_relattn,
    float* __restrict__ cur_term, float* __restrict__ nbr_proj,
    float* __restrict__ curwc)
{
  const int m    = blockIdx.x;
  const int lane = threadIdx.x;
  const float f0 = feats[m * D + lane];
  const float f1 = feats[m * D + 64 + lane];

  for (int r = 0; r < R; ++r) {
    const float* wsrow = W_state + r * WSTRIDE;
    float a = f0 * wsrow[D + lane] + f1 * wsrow[D + 64 + lane];
    for (int off = 32; off; off >>= 1) a += __shfl_xor(a, off);
    if (lane == 0) nbr_proj[m * R + r] = a;
    if (m >= 1) {
      float b = f0 * wsrow[lane] + f1 * wsrow[64 + lane];
      for (int off = 32; off; off >>= 1) b += __shfl_xor(b, off);
      if (lane == 0) cur_term[(m - 1) * R + r] = b;
    }
  }
  if (m >= 1) {
    float v = f0 * W_relattn[lane] + f1 * W_relattn[64 + lane];
    for (int off = 32; off; off >>= 1) v += __shfl_xor(v, off);
    if (lane == 0) curwc[m - 1] = v;
  }
}

// ---------------------------------------------------------------------------
// Kernel 3: fused attention (float4 gathers, stride-132 rr, wave-parallel D1).
// ---------------------------------------------------------------------------
__device__ __forceinline__ void store_out(void* out, int i, float v, int outf32) {
  if (outf32) ((float*)out)[i] = v;
  else        ((__hip_bfloat16*)out)[i] = __float2bfloat16(v);
}

__global__ __launch_bounds__(256) void attn_kernel(
    const float* __restrict__ feats, const int* __restrict__ neighbors,
    const float* __restrict__ W_state, const float* __restrict__ b_state,
    const float* __restrict__ W_relattn, const float* __restrict__ b_relattn,
    const float* __restrict__ W_pred, const float* __restrict__ b_pred,
    const float* __restrict__ cur_term, const float* __restrict__ nbr_proj,
    const float* __restrict__ curwc, const void* __restrict__ win_raw,
    void* __restrict__ out)
{
  const int n   = blockIdx.x;
  const int tid = threadIdx.x;

  __shared__ float rr[R * 132];     // rel_reps, stride 132 (16B-aligned rows)
  __shared__ int   idx_lds[R * NK];
  __shared__ float sc_lds[R * NK];
  __shared__ float w_lds[R * NK];
  __shared__ float ct_lds[R];
  __shared__ float rt_lds[R];
  __shared__ float s2_lds[R];
  __shared__ float aw_lds[R];
  __shared__ float upd_lds[D];
  __shared__ int   sflag;

  if (tid == 0) sflag = g_detect_f32(win_raw);
  if (tid < R) {
    ct_lds[tid] = cur_term[n * R + tid];
    rt_lds[tid] = W_state[tid * WSTRIDE + 2 * D + tid] + b_state[tid];
  }
  for (int i = tid; i < R * NK; i += 256) {
    const int r = i >> 4, k = i & 15;
    idx_lds[i] = neighbors[(r * N + n) * NK + k];
  }
  __syncthreads();
  const int outf32 = sflag;

  // B1: scores
  for (int i = tid; i < R * NK; i += 256) {
    const int r = i >> 4;
    float s = ct_lds[r] + nbr_proj[idx_lds[i] * R + r] + rt_lds[r];
    sc_lds[i] = fmaxf(s, 0.0f);
  }
  __syncthreads();

  // B2: softmax over K per r
  if (tid < R) {
    float mx = -1e30f;
#pragma unroll
    for (int k = 0; k < NK; ++k) mx = fmaxf(mx, sc_lds[tid * NK + k]);
    float sum = 0.0f;
#pragma unroll
    for (int k = 0; k < NK; ++k) {
      float e = __expf(sc_lds[tid * NK + k] - mx);
      w_lds[tid * NK + k] = e;
      sum += e;
    }
    const float inv = 1.0f / sum;
#pragma unroll
    for (int k = 0; k < NK; ++k) w_lds[tid * NK + k] *= inv;
  }
  __syncthreads();

  // C: rel_reps[r][d] = sum_k w * feats[idx][d], float4-vectorized
  {
    const int d4 = tid & 31;        // 32 groups of 4 consecutive d
    const int r0 = tid >> 5;        // 8 parallel r
    for (int r = r0; r < R; r += 8) {
      float4 acc = {0.f, 0.f, 0.f, 0.f};
#pragma unroll
      for (int k = 0; k < NK; ++k) {
        const int m = idx_lds[r * NK + k];
        const float4 fv = *(const float4*)&feats[m * D + d4 * 4];
        const float wv = w_lds[r * NK + k];
        acc.x = fmaf(wv, fv.x, acc.x);
        acc.y = fmaf(wv, fv.y, acc.y);
        acc.z = fmaf(wv, fv.z, acc.z);
        acc.w = fmaf(wv, fv.w, acc.w);
      }
      *(float4*)&rr[r * 132 + d4 * 4] = acc;
    }
  }
  __syncthreads();

  // D1: s2[r] = relu(curwc + rel_reps[r].wn + wr[r] + b), 4 waves parallel
  {
    const int wv = tid >> 6, ln = tid & 63;
    for (int r = wv; r < R; r += 4) {
      float a = rr[r * 132 + ln] * W_relattn[D + ln] +
                rr[r * 132 + 64 + ln] * W_relattn[D + 64 + ln];
      for (int off = 32; off; off >>= 1) a += __shfl_xor(a, off);
      if (ln == 0) {
        float v = curwc[n] + a + W_relattn[2 * D + r] + b_relattn[0];
        s2_lds[r] = fmaxf(v, 0.0f);
      }
    }
  }
  __syncthreads();

  // D2: softmax over r (wave 0)
  if (tid < 64) {
    float v = (tid < R) ? s2_lds[tid] : -1e30f;
    float mx = v;
    for (int off = 32; off; off >>= 1) mx = fmaxf(mx, __shfl_xor(mx, off));
    float e = (tid < R) ? __expf(v - mx) : 0.0f;
    float sum = e;
    for (int off = 32; off; off >>= 1) sum += __shfl_xor(sum, off);
    if (tid < R) aw_lds[tid] = e / sum;
  }
  __syncthreads();

  // E: rel_agg + updated
  if (tid < D) {
    float agg = 0.0f;
    for (int r = 0; r < R; ++r) agg = fmaf(aw_lds[r], rr[r * 132 + tid], agg);
    const float upd = feats[(n + 1) * D + tid] + agg;
    store_out(out, 2 * 3 * N + n * D + tid, upd, outf32);
    upd_lds[tid] = upd;
  }
  __syncthreads();

  // F: logits + prediction softmax (wave 0)
  if (tid < 64) {
    float p[3];
#pragma unroll
    for (int j = 0; j < 3; ++j) {
      float v = upd_lds[tid] * W_pred[tid * 3 + j] +
                upd_lds[tid + 64] * W_pred[(tid + 64) * 3 + j];
      for (int off = 32; off; off >>= 1) v += __shfl_xor(v, off);
      p[j] = v + b_pred[j];
    }
    if (tid == 0) {
      const float mx = fmaxf(p[0], fmaxf(p[1], p[2]));
      const float e0 = __expf(p[0] - mx), e1 = __expf(p[1] - mx), e2 = __expf(p[2] - mx);
      const float s = e0 + e1 + e2;
      store_out(out, n * 3 + 0, p[0], outf32);
      store_out(out, n * 3 + 1, p[1], outf32);
      store_out(out, n * 3 + 2, p[2], outf32);
      store_out(out, 3 * N + n * 3 + 0, e0 / s, outf32);
      store_out(out, 3 * N + n * 3 + 1, e1 / s, outf32);
      store_out(out, 3 * N + n * 3 + 2, e2 / s, outf32);
    }
  }
}

// ---------------------------------------------------------------------------
extern "C" void kernel_launch(void* const* d_in, const int* in_sizes, int n_in,
                              void* d_out, int out_size, void* d_ws, size_t ws_size,
                              hipStream_t stream)
{
  const int* neighbors = (const int*)d_in[1];
  float* ws = (float*)d_ws;

  constexpr int SZ[10] = {327680, 5120, 65536, 512, 18585, 59, 315, 1, 384, 3};
  CvtArgs ca;
  {
    int off = 0, k = 0;
    for (int i = 0; i < 11; ++i) {
      if (i == 1) continue;
      ca.src[k] = d_in[i];
      ca.off[k] = off;
      off += SZ[k];
      ++k;
    }
    ca.off[10] = off;   // 418195
  }
  float* cvt      = ws;
  float* feats    = cvt + 418208;
  float* cur_term = feats + 131200;
  float* nbr_proj = cur_term + 60416;
  float* curwc    = nbr_proj + 60480;

  const float* c_Wstate = cvt + 398848;
  const float* c_bstate = cvt + 417433;
  const float* c_Wrel   = cvt + 417492;
  const float* c_brel   = cvt + 417807;
  const float* c_Wpred  = cvt + 417808;
  const float* c_bpred  = cvt + 418192;

  convert_kernel<<<1024, 256, 0, stream>>>(ca, cvt);
  lstm_kernel<<<N / 8, 512, 0, stream>>>(cvt, feats);
  proj_kernel<<<N + 1, 64, 0, stream>>>(feats, c_Wstate, c_Wrel, cur_term, nbr_proj, curwc);
  attn_kernel<<<N, 256, 0, stream>>>(feats, neighbors, c_Wstate, c_bstate, c_Wrel,
                                     c_brel, c_Wpred, c_bpred,
                                     cur_term, nbr_proj, curwc, d_in[0], d_out);
}

// Round 4
// 143.217 us; speedup vs baseline: 1.7254x; 1.2050x over previous
//
#include <hip/hip_runtime.h>
#include <hip/hip_bf16.h>

// Problem constants
constexpr int R  = 59;
constexpr int D  = 128;
constexpr int NK = 16;      // neighbors per (r,n)
constexpr int N  = 1024;
constexpr int T  = 32;
constexpr int F  = 10;
constexpr int H4 = 512;     // 4*D
constexpr int WSTRIDE = 2*D + R; // 315

typedef __attribute__((ext_vector_type(8))) short short8;   // 8 bf16 (4 VGPR)
typedef __attribute__((ext_vector_type(4))) float f32x4;    // MFMA C/D

__device__ __forceinline__ float sigm(float x) {
  return __builtin_amdgcn_rcpf(1.0f + __expf(-x));
}
__device__ __forceinline__ float tanh_(float x) {
  return 2.0f * __builtin_amdgcn_rcpf(1.0f + __expf(-2.0f * x)) - 1.0f;
}
__device__ __forceinline__ ushort f2bf(float f) {          // RNE fp32->bf16
  unsigned u = __float_as_uint(f);
  u += 0x7FFF + ((u >> 16) & 1);
  return (ushort)(u >> 16);
}

// ---------------------------------------------------------------------------
// Runtime dtype detection (proven round 2). Computed once in convert_kernel.
// ---------------------------------------------------------------------------
__device__ int g_detect_f32(const void* windows) {
  const __hip_bfloat16* p = (const __hip_bfloat16*)windows;
  int weird = 0;
  for (int i = 0; i < 128; ++i) {
    float v = __bfloat162float(p[i]);
    float a = fabsf(v);
    if (!(a <= 100.0f) || (v != 0.0f && a < 1e-8f)) ++weird;
  }
  return weird > 8;
}

struct CvtArgs {
  const void* src[10];
  int off[11];
};

__global__ __launch_bounds__(256) void convert_kernel(CvtArgs a, float* __restrict__ dst,
                                                      int* __restrict__ flag_out) {
  __shared__ int sflag;
  if (threadIdx.x == 0) sflag = g_detect_f32(a.src[0]);
  __syncthreads();
  const int isf32 = sflag;
  if (blockIdx.x == 0 && threadIdx.x == 0) flag_out[0] = isf32;
  const int total = a.off[10];
  for (int i = blockIdx.x * 256 + threadIdx.x; i < total; i += gridDim.x * 256) {
    int t = 0;
    while (t < 9 && i >= a.off[t + 1]) ++t;
    const int j = i - a.off[t];
    dst[i] = isf32 ? ((const float*)a.src[t])[j]
                   : __bfloat162float(((const __hip_bfloat16*)a.src[t])[j]);
  }
}

// ---------------------------------------------------------------------------
// Kernel 1: MFMA LSTM. 128 blocks x 8 samples, 512 threads = 8 waves.
// Z[8,512] = [h|x] @ [Wr;Wk] per step via mfma_f32_16x16x32_bf16.
// Wave w owns cols [16w,16w+16) of EACH gate; gate pointwise lane-local.
// launch_bounds(512,1): 256-VGPR budget so the 80-VGPR B fragments STAY
// RESIDENT (512,2 capped at 128 VGPR and spilled them -> 2us/step).
// ---------------------------------------------------------------------------
__global__ __launch_bounds__(512, 1) void lstm_kernel(
    const float* __restrict__ cvt, float* __restrict__ feats)
{
  const float* Wwin = cvt;                 // [1024][32][10]
  const float* Wk   = cvt + 327680;        // [10][512]
  const float* Wr   = cvt + 332800;        // [128][512]
  const float* bias = cvt + 398336;        // [512]

  const int tid = threadIdx.x;
  const int w   = tid >> 6;    // wave 0..7
  const int l   = tid & 63;    // lane
  const int n0  = blockIdx.x * 8;

  __shared__ ushort hbuf[2][16 * 136];     // bf16 h, double-buffered, padded
  __shared__ ushort xfrag[T * 64 * 8];     // prebuilt A-frags for x (32 KB)

  if (blockIdx.x == 0 && tid < D) feats[tid] = 0.0f;   // feats row 0 = 0

  // Prebuild per-t x A-fragments: lane ll -> row=ll&15, k-chunk=ll>>4.
  for (int p = tid; p < T * 64; p += 512) {
    const int t = p >> 6, ll = p & 63, row = ll & 15, kg = ll >> 4;
#pragma unroll
    for (int j = 0; j < 8; ++j) {
      const int f = kg * 8 + j;
      float x = (row < 8 && f < F) ? Wwin[(n0 + row) * (T * F) + t * F + f] : 0.0f;
      xfrag[p * 8 + j] = f2bf(x);
    }
  }
  for (int i = tid; i < 2 * 16 * 136; i += 512) ((ushort*)hbuf)[i] = 0;

  // Persistent B fragments: [gate][kfrag]; kfrag 0..3 = Wr rows, 4 = Wk (pad 0).
  const int dcol  = w * 16 + (l & 15);     // this lane's d within [0,128)
  const int krow0 = (l >> 4) * 8;
  short8 B[4][5];
#pragma unroll
  for (int g = 0; g < 4; ++g) {
    const int col = g * D + dcol;
#pragma unroll
    for (int kf = 0; kf < 5; ++kf) {
      short8 bb;
#pragma unroll
      for (int j = 0; j < 8; ++j) {
        float v;
        if (kf < 4) v = Wr[(kf * 32 + krow0 + j) * H4 + col];
        else {
          const int f = krow0 + j;
          v = (f < F) ? Wk[f * H4 + col] : 0.0f;
        }
        bb[j] = (short)f2bf(v);
      }
      B[g][kf] = bb;
    }
  }
  float bi[4];
#pragma unroll
  for (int g = 0; g < 4; ++g) bi[g] = bias[g * D + dcol];

  f32x4 c4 = {0.f, 0.f, 0.f, 0.f};
  float hreg[4] = {0.f, 0.f, 0.f, 0.f};
  const int rb = (l >> 4) * 4;             // C-layout row base for this lane

  __syncthreads();

  for (int t = 0; t < T; ++t) {
    const ushort* hb = hbuf[t & 1];
    short8 A[5];
#pragma unroll
    for (int kf = 0; kf < 4; ++kf)
      A[kf] = *(const short8*)(hb + (l & 15) * 136 + kf * 32 + krow0);
    A[4] = *(const short8*)(xfrag + (t * 64 + l) * 8);

    f32x4 acc[4];
#pragma unroll
    for (int g = 0; g < 4; ++g) {
      acc[g] = (f32x4){0.f, 0.f, 0.f, 0.f};
#pragma unroll
      for (int kf = 0; kf < 5; ++kf)
        acc[g] = __builtin_amdgcn_mfma_f32_16x16x32_bf16(A[kf], B[g][kf], acc[g], 0, 0, 0);
    }

    ushort* hw = hbuf[(t + 1) & 1];
#pragma unroll
    for (int r = 0; r < 4; ++r) {
      const float i_ = sigm(acc[0][r] + bi[0]);
      const float f_ = sigm(acc[1][r] + bi[1]);
      const float g_ = tanh_(acc[2][r] + bi[2]);
      const float o_ = sigm(acc[3][r] + bi[3]);
      c4[r]   = f_ * c4[r] + i_ * g_;
      hreg[r] = o_ * tanh_(c4[r]);
      if (rb + r < 8) hw[(rb + r) * 136 + dcol] = f2bf(hreg[r]);
    }
    __syncthreads();
  }

#pragma unroll
  for (int r = 0; r < 4; ++r)
    if (rb + r < 8) feats[(n0 + rb + r + 1) * D + dcol] = hreg[r];
}

// ---------------------------------------------------------------------------
// Kernel 2: projections. 4 feats-rows per 256-thread block, one wave each.
// ---------------------------------------------------------------------------
__global__ __launch_bounds__(256) void proj_kernel(
    const float* __restrict__ feats, const float* __restrict__ W_state,
    const float* __restrict__ W_relattn,
    float* __restrict__ cur_term, float* __restrict__ nbr_proj,
    float* __restrict__ curwc)
{
  const int m = blockIdx.x * 4 + (threadIdx.x >> 6);
  if (m > N) return;
  const int lane = threadIdx.x & 63;
  const float f0 = feats[m * D + lane];
  const float f1 = feats[m * D + 64 + lane];

  for (int r = 0; r < R; ++r) {
    const float* wsrow = W_state + r * WSTRIDE;
    float a = f0 * wsrow[D + lane] + f1 * wsrow[D + 64 + lane];
    for (int off = 32; off; off >>= 1) a += __shfl_xor(a, off);
    if (lane == 0) nbr_proj[m * R + r] = a;
    if (m >= 1) {
      float b = f0 * wsrow[lane] + f1 * wsrow[64 + lane];
      for (int off = 32; off; off >>= 1) b += __shfl_xor(b, off);
      if (lane == 0) cur_term[(m - 1) * R + r] = b;
    }
  }
  if (m >= 1) {
    float v = f0 * W_relattn[lane] + f1 * W_relattn[64 + lane];
    for (int off = 32; off; off >>= 1) v += __shfl_xor(v, off);
    if (lane == 0) curwc[m - 1] = v;
  }
}

// ---------------------------------------------------------------------------
// Kernel 3: fused attention.
// ---------------------------------------------------------------------------
__device__ __forceinline__ void store_out(void* out, int i, float v, int outf32) {
  if (outf32) ((float*)out)[i] = v;
  else        ((__hip_bfloat16*)out)[i] = __float2bfloat16(v);
}

__global__ __launch_bounds__(256) void attn_kernel(
    const float* __restrict__ feats, const int* __restrict__ neighbors,
    const float* __restrict__ W_state, const float* __restrict__ b_state,
    const float* __restrict__ W_relattn, const float* __restrict__ b_relattn,
    const float* __restrict__ W_pred, const float* __restrict__ b_pred,
    const float* __restrict__ cur_term, const float* __restrict__ nbr_proj,
    const float* __restrict__ curwc, const int* __restrict__ flagp,
    void* __restrict__ out)
{
  const int n   = blockIdx.x;
  const int tid = threadIdx.x;

  __shared__ float rr[R * 132];     // rel_reps, stride 132 (16B-aligned rows)
  __shared__ int   idx_lds[R * NK];
  __shared__ float sc_lds[R * NK];
  __shared__ float w_lds[R * NK];
  __shared__ float ct_lds[R];
  __shared__ float rt_lds[R];
  __shared__ float s2_lds[R];
  __shared__ float aw_lds[R];
  __shared__ float upd_lds[D];
  __shared__ int   sflag;

  if (tid == 0) sflag = flagp[0];
  if (tid < R) {
    ct_lds[tid] = cur_term[n * R + tid];
    rt_lds[tid] = W_state[tid * WSTRIDE + 2 * D + tid] + b_state[tid];
  }
  for (int i = tid; i < R * NK; i += 256) {
    const int r = i >> 4, k = i & 15;
    idx_lds[i] = neighbors[(r * N + n) * NK + k];
  }
  __syncthreads();
  const int outf32 = sflag;

  // B1: scores
  for (int i = tid; i < R * NK; i += 256) {
    const int r = i >> 4;
    float s = ct_lds[r] + nbr_proj[idx_lds[i] * R + r] + rt_lds[r];
    sc_lds[i] = fmaxf(s, 0.0f);
  }
  __syncthreads();

  // B2: softmax over K per r
  if (tid < R) {
    float mx = -1e30f;
#pragma unroll
    for (int k = 0; k < NK; ++k) mx = fmaxf(mx, sc_lds[tid * NK + k]);
    float sum = 0.0f;
#pragma unroll
    for (int k = 0; k < NK; ++k) {
      float e = __expf(sc_lds[tid * NK + k] - mx);
      w_lds[tid * NK + k] = e;
      sum += e;
    }
    const float inv = __builtin_amdgcn_rcpf(sum);
#pragma unroll
    for (int k = 0; k < NK; ++k) w_lds[tid * NK + k] *= inv;
  }
  __syncthreads();

  // C: rel_reps[r][d] = sum_k w * feats[idx][d], float4-vectorized
  {
    const int d4 = tid & 31;
    const int r0 = tid >> 5;
    for (int r = r0; r < R; r += 8) {
      float4 acc = {0.f, 0.f, 0.f, 0.f};
#pragma unroll
      for (int k = 0; k < NK; ++k) {
        const int m = idx_lds[r * NK + k];
        const float4 fv = *(const float4*)&feats[m * D + d4 * 4];
        const float wv = w_lds[r * NK + k];
        acc.x = fmaf(wv, fv.x, acc.x);
        acc.y = fmaf(wv, fv.y, acc.y);
        acc.z = fmaf(wv, fv.z, acc.z);
        acc.w = fmaf(wv, fv.w, acc.w);
      }
      *(float4*)&rr[r * 132 + d4 * 4] = acc;
    }
  }
  __syncthreads();

  // D1: s2[r] = relu(curwc + rel_reps[r].wn + wr[r] + b), 4 waves parallel
  {
    const int wv = tid >> 6, ln = tid & 63;
    for (int r = wv; r < R; r += 4) {
      float a = rr[r * 132 + ln] * W_relattn[D + ln] +
                rr[r * 132 + 64 + ln] * W_relattn[D + 64 + ln];
      for (int off = 32; off; off >>= 1) a += __shfl_xor(a, off);
      if (ln == 0) {
        float v = curwc[n] + a + W_relattn[2 * D + r] + b_relattn[0];
        s2_lds[r] = fmaxf(v, 0.0f);
      }
    }
  }
  __syncthreads();

  // D2: softmax over r (wave 0)
  if (tid < 64) {
    float v = (tid < R) ? s2_lds[tid] : -1e30f;
    float mx = v;
    for (int off = 32; off; off >>= 1) mx = fmaxf(mx, __shfl_xor(mx, off));
    float e = (tid < R) ? __expf(v - mx) : 0.0f;
    float sum = e;
    for (int off = 32; off; off >>= 1) sum += __shfl_xor(sum, off);
    if (tid < R) aw_lds[tid] = e / sum;
  }
  __syncthreads();

  // E: rel_agg + updated
  if (tid < D) {
    float agg = 0.0f;
    for (int r = 0; r < R; ++r) agg = fmaf(aw_lds[r], rr[r * 132 + tid], agg);
    const float upd = feats[(n + 1) * D + tid] + agg;
    store_out(out, 2 * 3 * N + n * D + tid, upd, outf32);
    upd_lds[tid] = upd;
  }
  __syncthreads();

  // F: logits + prediction softmax (wave 0)
  if (tid < 64) {
    float p[3];
#pragma unroll
    for (int j = 0; j < 3; ++j) {
      float v = upd_lds[tid] * W_pred[tid * 3 + j] +
                upd_lds[tid + 64] * W_pred[(tid + 64) * 3 + j];
      for (int off = 32; off; off >>= 1) v += __shfl_xor(v, off);
      p[j] = v + b_pred[j];
    }
    if (tid == 0) {
      const float mx = fmaxf(p[0], fmaxf(p[1], p[2]));
      const float e0 = __expf(p[0] - mx), e1 = __expf(p[1] - mx), e2 = __expf(p[2] - mx);
      const float s = e0 + e1 + e2;
      store_out(out, n * 3 + 0, p[0], outf32);
      store_out(out, n * 3 + 1, p[1], outf32);
      store_out(out, n * 3 + 2, p[2], outf32);
      store_out(out, 3 * N + n * 3 + 0, e0 / s, outf32);
      store_out(out, 3 * N + n * 3 + 1, e1 / s, outf32);
      store_out(out, 3 * N + n * 3 + 2, e2 / s, outf32);
    }
  }
}

// ---------------------------------------------------------------------------
extern "C" void kernel_launch(void* const* d_in, const int* in_sizes, int n_in,
                              void* d_out, int out_size, void* d_ws, size_t ws_size,
                              hipStream_t stream)
{
  const int* neighbors = (const int*)d_in[1];
  float* ws = (float*)d_ws;

  constexpr int SZ[10] = {327680, 5120, 65536, 512, 18585, 59, 315, 1, 384, 3};
  CvtArgs ca;
  {
    int off = 0, k = 0;
    for (int i = 0; i < 11; ++i) {
      if (i == 1) continue;
      ca.src[k] = d_in[i];
      ca.off[k] = off;
      off += SZ[k];
      ++k;
    }
    ca.off[10] = off;   // 418195
  }
  float* cvt      = ws;
  float* feats    = cvt + 418208;
  float* cur_term = feats + 131200;
  float* nbr_proj = cur_term + 60416;
  float* curwc    = nbr_proj + 60480;
  int*   flagp    = (int*)(curwc + 1024);

  const float* c_Wstate = cvt + 398848;
  const float* c_bstate = cvt + 417433;
  const float* c_Wrel   = cvt + 417492;
  const float* c_brel   = cvt + 417807;
  const float* c_Wpred  = cvt + 417808;
  const float* c_bpred  = cvt + 418192;

  convert_kernel<<<1024, 256, 0, stream>>>(ca, cvt, flagp);
  lstm_kernel<<<N / 8, 512, 0, stream>>>(cvt, feats);
  proj_kernel<<<(N + 4) / 4, 256, 0, stream>>>(feats, c_Wstate, c_Wrel, cur_term, nbr_proj, curwc);
  attn_kernel<<<N, 256, 0, stream>>>(feats, neighbors, c_Wstate, c_bstate, c_Wrel,
                                     c_brel, c_Wpred, c_bpred,
                                     cur_term, nbr_proj, curwc, flagp, d_out);
}

// Round 5
// 97.560 us; speedup vs baseline: 2.5329x; 1.4680x over previous
//
#include <hip/hip_runtime.h>
#include <hip/hip_bf16.h>

// Problem constants
constexpr int R  = 59;
constexpr int D  = 128;
constexpr int NK = 16;      // neighbors per (r,n)
constexpr int N  = 1024;
constexpr int T  = 32;
constexpr int F  = 10;
constexpr int H4 = 512;     // 4*D
constexpr int WSTRIDE = 2*D + R; // 315

typedef __attribute__((ext_vector_type(8))) short short8;   // 8 bf16 (4 VGPR)
typedef __attribute__((ext_vector_type(4))) float f32x4;    // MFMA C/D

__device__ __forceinline__ float sigm(float x) {
  return __builtin_amdgcn_rcpf(1.0f + __expf(-x));
}
__device__ __forceinline__ float tanh_(float x) {
  return 2.0f * __builtin_amdgcn_rcpf(1.0f + __expf(-2.0f * x)) - 1.0f;
}
__device__ __forceinline__ ushort f2bf(float f) {          // RNE fp32->bf16
  unsigned u = __float_as_uint(f);
  u += 0x7FFF + ((u >> 16) & 1);
  return (ushort)(u >> 16);
}

// ---------------------------------------------------------------------------
// Runtime dtype detection (proven round 2). Computed once in convert_kernel.
// ---------------------------------------------------------------------------
__device__ int g_detect_f32(const void* windows) {
  const __hip_bfloat16* p = (const __hip_bfloat16*)windows;
  int weird = 0;
  for (int i = 0; i < 128; ++i) {
    float v = __bfloat162float(p[i]);
    float a = fabsf(v);
    if (!(a <= 100.0f) || (v != 0.0f && a < 1e-8f)) ++weird;
  }
  return weird > 8;
}

__device__ __forceinline__ float rdsrc(const void* p, int i, int isf32) {
  return isf32 ? ((const float*)p)[i]
               : __bfloat162float(((const __hip_bfloat16*)p)[i]);
}

struct CvtArgs {
  const void* src[10];
  int off[11];
};

// Converts all float tensors to fp32 AND packs Wt[d][j] (j: 59 Wn | 59 Wc | wc)
// for the coalesced proj kernel.
__global__ __launch_bounds__(256) void convert_kernel(CvtArgs a, float* __restrict__ dst,
                                                      float* __restrict__ wt,
                                                      int* __restrict__ flag_out) {
  __shared__ int sflag;
  if (threadIdx.x == 0) sflag = g_detect_f32(a.src[0]);
  __syncthreads();
  const int isf32 = sflag;
  if (blockIdx.x == 0 && threadIdx.x == 0) flag_out[0] = isf32;
  const int total = a.off[10];
  for (int i = blockIdx.x * 256 + threadIdx.x; i < total; i += gridDim.x * 256) {
    int t = 0;
    while (t < 9 && i >= a.off[t + 1]) ++t;
    const int j = i - a.off[t];
    dst[i] = isf32 ? ((const float*)a.src[t])[j]
                   : __bfloat162float(((const __hip_bfloat16*)a.src[t])[j]);
  }
  // pack Wt: 128 x 128 (cols 119..127 zero)
  for (int i = blockIdx.x * 256 + threadIdx.x; i < 128 * 128; i += gridDim.x * 256) {
    const int d = i >> 7, j = i & 127;
    float v = 0.0f;
    if (j < 59)        v = rdsrc(a.src[4], j * WSTRIDE + D + d, isf32);         // Wn
    else if (j < 118)  v = rdsrc(a.src[4], (j - 59) * WSTRIDE + d, isf32);      // Wc
    else if (j == 118) v = rdsrc(a.src[6], d, isf32);                           // wc
    wt[i] = v;
  }
}

// ---------------------------------------------------------------------------
// Kernel 1: MFMA LSTM. 128 blocks x 8 samples, 512 threads = 8 waves.
// Z[8,512] = [h|x] @ [Wr;Wk] per step via mfma_f32_16x16x32_bf16.
// Wave w owns cols [16w,16w+16) of EACH gate; gate pointwise lane-local.
// launch_bounds(512,1): 256-VGPR budget so the 80-VGPR B fragments STAY
// RESIDENT (512,2 capped at 128 VGPR and spilled them -> 2us/step).
// ---------------------------------------------------------------------------
__global__ __launch_bounds__(512, 1) void lstm_kernel(
    const float* __restrict__ cvt, float* __restrict__ feats)
{
  const float* Wwin = cvt;                 // [1024][32][10]
  const float* Wk   = cvt + 327680;        // [10][512]
  const float* Wr   = cvt + 332800;        // [128][512]
  const float* bias = cvt + 398336;        // [512]

  const int tid = threadIdx.x;
  const int w   = tid >> 6;    // wave 0..7
  const int l   = tid & 63;    // lane
  const int n0  = blockIdx.x * 8;

  __shared__ ushort hbuf[2][16 * 136];     // bf16 h, double-buffered, padded
  __shared__ ushort xfrag[T * 64 * 8];     // prebuilt A-frags for x (32 KB)

  if (blockIdx.x == 0 && tid < D) feats[tid] = 0.0f;   // feats row 0 = 0

  // Prebuild per-t x A-fragments: lane ll -> row=ll&15, k-chunk=ll>>4.
  for (int p = tid; p < T * 64; p += 512) {
    const int t = p >> 6, ll = p & 63, row = ll & 15, kg = ll >> 4;
#pragma unroll
    for (int j = 0; j < 8; ++j) {
      const int f = kg * 8 + j;
      float x = (row < 8 && f < F) ? Wwin[(n0 + row) * (T * F) + t * F + f] : 0.0f;
      xfrag[p * 8 + j] = f2bf(x);
    }
  }
  for (int i = tid; i < 2 * 16 * 136; i += 512) ((ushort*)hbuf)[i] = 0;

  // Persistent B fragments: [gate][kfrag]; kfrag 0..3 = Wr rows, 4 = Wk (pad 0).
  const int dcol  = w * 16 + (l & 15);     // this lane's d within [0,128)
  const int krow0 = (l >> 4) * 8;
  short8 B[4][5];
#pragma unroll
  for (int g = 0; g < 4; ++g) {
    const int col = g * D + dcol;
#pragma unroll
    for (int kf = 0; kf < 5; ++kf) {
      short8 bb;
#pragma unroll
      for (int j = 0; j < 8; ++j) {
        float v;
        if (kf < 4) v = Wr[(kf * 32 + krow0 + j) * H4 + col];
        else {
          const int f = krow0 + j;
          v = (f < F) ? Wk[f * H4 + col] : 0.0f;
        }
        bb[j] = (short)f2bf(v);
      }
      B[g][kf] = bb;
    }
  }
  float bi[4];
#pragma unroll
  for (int g = 0; g < 4; ++g) bi[g] = bias[g * D + dcol];

  f32x4 c4 = {0.f, 0.f, 0.f, 0.f};
  float hreg[4] = {0.f, 0.f, 0.f, 0.f};
  const int rb = (l >> 4) * 4;             // C-layout row base for this lane

  __syncthreads();

  for (int t = 0; t < T; ++t) {
    const ushort* hb = hbuf[t & 1];
    short8 A[5];
#pragma unroll
    for (int kf = 0; kf < 4; ++kf)
      A[kf] = *(const short8*)(hb + (l & 15) * 136 + kf * 32 + krow0);
    A[4] = *(const short8*)(xfrag + (t * 64 + l) * 8);

    f32x4 acc[4];
#pragma unroll
    for (int g = 0; g < 4; ++g) {
      acc[g] = (f32x4){0.f, 0.f, 0.f, 0.f};
#pragma unroll
      for (int kf = 0; kf < 5; ++kf)
        acc[g] = __builtin_amdgcn_mfma_f32_16x16x32_bf16(A[kf], B[g][kf], acc[g], 0, 0, 0);
    }

    ushort* hw = hbuf[(t + 1) & 1];
#pragma unroll
    for (int r = 0; r < 4; ++r) {
      const float i_ = sigm(acc[0][r] + bi[0]);
      const float f_ = sigm(acc[1][r] + bi[1]);
      const float g_ = tanh_(acc[2][r] + bi[2]);
      const float o_ = sigm(acc[3][r] + bi[3]);
      c4[r]   = f_ * c4[r] + i_ * g_;
      hreg[r] = o_ * tanh_(c4[r]);
      if (rb + r < 8) hw[(rb + r) * 136 + dcol] = f2bf(hreg[r]);
    }
    __syncthreads();
  }

#pragma unroll
  for (int r = 0; r < 4; ++r)
    if (rb + r < 8) feats[(n0 + rb + r + 1) * D + dcol] = hreg[r];
}

// ---------------------------------------------------------------------------
// Kernel 2: projections, data-parallel. One block per feats row m.
// Thread j computes output j of feats[m] @ Wt  (j<59: Wn -> nbr_proj,
// 59<=j<118: Wc -> cur_term, j==118: wc -> curwc). Coalesced Wt reads,
// LDS-broadcast feats row, zero shuffles.
// ---------------------------------------------------------------------------
__global__ __launch_bounds__(128) void proj_kernel(
    const float* __restrict__ feats, const float* __restrict__ wt,
    float* __restrict__ cur_term, float* __restrict__ nbr_proj,
    float* __restrict__ curwc)
{
  const int m = blockIdx.x;      // 0..1024
  const int j = threadIdx.x;     // 0..127
  __shared__ float frow[128];
  frow[j] = feats[m * D + j];
  __syncthreads();

  float acc = 0.0f;
#pragma unroll 8
  for (int d = 0; d < 128; ++d)
    acc = fmaf(frow[d], wt[d * 128 + j], acc);

  if (j < 59) nbr_proj[m * R + j] = acc;
  else if (m >= 1) {
    if (j < 118)       cur_term[(m - 1) * R + (j - 59)] = acc;
    else if (j == 118) curwc[m - 1] = acc;
  }
}

// ---------------------------------------------------------------------------
// Kernel 3: fused attention.
// ---------------------------------------------------------------------------
__device__ __forceinline__ void store_out(void* out, int i, float v, int outf32) {
  if (outf32) ((float*)out)[i] = v;
  else        ((__hip_bfloat16*)out)[i] = __float2bfloat16(v);
}

__global__ __launch_bounds__(256) void attn_kernel(
    const float* __restrict__ feats, const int* __restrict__ neighbors,
    const float* __restrict__ W_state, const float* __restrict__ b_state,
    const float* __restrict__ W_relattn, const float* __restrict__ b_relattn,
    const float* __restrict__ W_pred, const float* __restrict__ b_pred,
    const float* __restrict__ cur_term, const float* __restrict__ nbr_proj,
    const float* __restrict__ curwc, const int* __restrict__ flagp,
    void* __restrict__ out)
{
  const int n   = blockIdx.x;
  const int tid = threadIdx.x;

  __shared__ float rr[R * 132];     // rel_reps, stride 132 (16B-aligned rows)
  __shared__ int   idx_lds[R * NK];
  __shared__ float sc_lds[R * NK];
  __shared__ float w_lds[R * NK];
  __shared__ float ct_lds[R];
  __shared__ float rt_lds[R];
  __shared__ float s2_lds[R];
  __shared__ float aw_lds[R];
  __shared__ float upd_lds[D];
  __shared__ int   sflag;

  if (tid == 0) sflag = flagp[0];
  if (tid < R) {
    ct_lds[tid] = cur_term[n * R + tid];
    rt_lds[tid] = W_state[tid * WSTRIDE + 2 * D + tid] + b_state[tid];
  }
  for (int i = tid; i < R * NK; i += 256) {
    const int r = i >> 4, k = i & 15;
    idx_lds[i] = neighbors[(r * N + n) * NK + k];
  }
  __syncthreads();
  const int outf32 = sflag;

  // B1: scores
  for (int i = tid; i < R * NK; i += 256) {
    const int r = i >> 4;
    float s = ct_lds[r] + nbr_proj[idx_lds[i] * R + r] + rt_lds[r];
    sc_lds[i] = fmaxf(s, 0.0f);
  }
  __syncthreads();

  // B2: softmax over K per r
  if (tid < R) {
    float mx = -1e30f;
#pragma unroll
    for (int k = 0; k < NK; ++k) mx = fmaxf(mx, sc_lds[tid * NK + k]);
    float sum = 0.0f;
#pragma unroll
    for (int k = 0; k < NK; ++k) {
      float e = __expf(sc_lds[tid * NK + k] - mx);
      w_lds[tid * NK + k] = e;
      sum += e;
    }
    const float inv = __builtin_amdgcn_rcpf(sum);
#pragma unroll
    for (int k = 0; k < NK; ++k) w_lds[tid * NK + k] *= inv;
  }
  __syncthreads();

  // C: rel_reps[r][d] = sum_k w * feats[idx][d], float4-vectorized
  {
    const int d4 = tid & 31;
    const int r0 = tid >> 5;
    for (int r = r0; r < R; r += 8) {
      float4 acc = {0.f, 0.f, 0.f, 0.f};
#pragma unroll
      for (int k = 0; k < NK; ++k) {
        const int m = idx_lds[r * NK + k];
        const float4 fv = *(const float4*)&feats[m * D + d4 * 4];
        const float wv = w_lds[r * NK + k];
        acc.x = fmaf(wv, fv.x, acc.x);
        acc.y = fmaf(wv, fv.y, acc.y);
        acc.z = fmaf(wv, fv.z, acc.z);
        acc.w = fmaf(wv, fv.w, acc.w);
      }
      *(float4*)&rr[r * 132 + d4 * 4] = acc;
    }
  }
  __syncthreads();

  // D1: s2[r] = relu(curwc + rel_reps[r].wn + wr[r] + b), 4 waves parallel
  {
    const int wv = tid >> 6, ln = tid & 63;
    for (int r = wv; r < R; r += 4) {
      float a = rr[r * 132 + ln] * W_relattn[D + ln] +
                rr[r * 132 + 64 + ln] * W_relattn[D + 64 + ln];
      for (int off = 32; off; off >>= 1) a += __shfl_xor(a, off);
      if (ln == 0) {
        float v = curwc[n] + a + W_relattn[2 * D + r] + b_relattn[0];
        s2_lds[r] = fmaxf(v, 0.0f);
      }
    }
  }
  __syncthreads();

  // D2: softmax over r (wave 0)
  if (tid < 64) {
    float v = (tid < R) ? s2_lds[tid] : -1e30f;
    float mx = v;
    for (int off = 32; off; off >>= 1) mx = fmaxf(mx, __shfl_xor(mx, off));
    float e = (tid < R) ? __expf(v - mx) : 0.0f;
    float sum = e;
    for (int off = 32; off; off >>= 1) sum += __shfl_xor(sum, off);
    if (tid < R) aw_lds[tid] = e / sum;
  }
  __syncthreads();

  // E: rel_agg + updated
  if (tid < D) {
    float agg = 0.0f;
    for (int r = 0; r < R; ++r) agg = fmaf(aw_lds[r], rr[r * 132 + tid], agg);
    const float upd = feats[(n + 1) * D + tid] + agg;
    store_out(out, 2 * 3 * N + n * D + tid, upd, outf32);
    upd_lds[tid] = upd;
  }
  __syncthreads();

  // F: logits + prediction softmax (wave 0)
  if (tid < 64) {
    float p[3];
#pragma unroll
    for (int j = 0; j < 3; ++j) {
      float v = upd_lds[tid] * W_pred[tid * 3 + j] +
                upd_lds[tid + 64] * W_pred[(tid + 64) * 3 + j];
      for (int off = 32; off; off >>= 1) v += __shfl_xor(v, off);
      p[j] = v + b_pred[j];
    }
    if (tid == 0) {
      const float mx = fmaxf(p[0], fmaxf(p[1], p[2]));
      const float e0 = __expf(p[0] - mx), e1 = __expf(p[1] - mx), e2 = __expf(p[2] - mx);
      const float s = e0 + e1 + e2;
      store_out(out, n * 3 + 0, p[0], outf32);
      store_out(out, n * 3 + 1, p[1], outf32);
      store_out(out, n * 3 + 2, p[2], outf32);
      store_out(out, 3 * N + n * 3 + 0, e0 / s, outf32);
      store_out(out, 3 * N + n * 3 + 1, e1 / s, outf32);
      store_out(out, 3 * N + n * 3 + 2, e2 / s, outf32);
    }
  }
}

// ---------------------------------------------------------------------------
extern "C" void kernel_launch(void* const* d_in, const int* in_sizes, int n_in,
                              void* d_out, int out_size, void* d_ws, size_t ws_size,
                              hipStream_t stream)
{
  const int* neighbors = (const int*)d_in[1];
  float* ws = (float*)d_ws;

  constexpr int SZ[10] = {327680, 5120, 65536, 512, 18585, 59, 315, 1, 384, 3};
  CvtArgs ca;
  {
    int off = 0, k = 0;
    for (int i = 0; i < 11; ++i) {
      if (i == 1) continue;
      ca.src[k] = d_in[i];
      ca.off[k] = off;
      off += SZ[k];
      ++k;
    }
    ca.off[10] = off;   // 418195
  }
  float* cvt      = ws;                    // 418195
  float* wtpack   = cvt + 418208;          // 16384 (128x128)
  float* feats    = wtpack + 16384;        // 131200
  float* cur_term = feats + 131200;        // 60416
  float* nbr_proj = cur_term + 60416;      // 60475 (+pad)
  float* curwc    = nbr_proj + 60480;      // 1024
  int*   flagp    = (int*)(curwc + 1024);

  const float* c_Wstate = cvt + 398848;
  const float* c_bstate = cvt + 417433;
  const float* c_Wrel   = cvt + 417492;
  const float* c_brel   = cvt + 417807;
  const float* c_Wpred  = cvt + 417808;
  const float* c_bpred  = cvt + 418192;

  convert_kernel<<<1024, 256, 0, stream>>>(ca, cvt, wtpack, flagp);
  lstm_kernel<<<N / 8, 512, 0, stream>>>(cvt, feats);
  proj_kernel<<<N + 1, 128, 0, stream>>>(feats, wtpack, cur_term, nbr_proj, curwc);
  attn_kernel<<<N, 256, 0, stream>>>(feats, neighbors, c_Wstate, c_bstate, c_Wrel,
                                     c_brel, c_Wpred, c_bpred,
                                     cur_term, nbr_proj, curwc, flagp, d_out);
}